// Round 10
// baseline (252.267 us; speedup 1.0000x reference)
//
#include <hip/hip_runtime.h>
#include <cstdint>
#include <cstddef>

// ---- types ----
typedef __attribute__((ext_vector_type(8))) short short8;       // 8 bf16 (4 VGPR) MFMA frag
typedef __attribute__((ext_vector_type(4))) float floatx4;      // MFMA accumulator
typedef __attribute__((ext_vector_type(4))) unsigned short ushortx4; // 8B packed bf16 store

#define MFMA16(a, b, c) __builtin_amdgcn_mfma_f32_16x16x32_bf16((a), (b), (c), 0, 0, 0)

__device__ __forceinline__ unsigned short f2bf(float f) {
  unsigned int u = __builtin_bit_cast(unsigned int, f);
  u += 0x7fffu + ((u >> 16) & 1u);          // RNE
  return (unsigned short)(u >> 16);
}

typedef __attribute__((address_space(1))) void gvoid_t;
typedef __attribute__((address_space(3))) void svoid_t;
__device__ __forceinline__ void gload_lds16(const void* g, void* l) {
  // LDS dest = wave-uniform base + lane*16; global side is per-lane addresses.
  __builtin_amdgcn_global_load_lds((gvoid_t*)(uintptr_t)g, (svoid_t*)(uintptr_t)l, 16, 0, 0);
}

// ---------------- convert x: fp32 -> bf16 ----------------
__global__ void convert_x(const float* __restrict__ x, unsigned short* __restrict__ xb) {
  int i = (blockIdx.x * 256 + threadIdx.x) * 4;
  floatx4 v = *(const floatx4*)(x + i);
  ushortx4 o;
  o[0] = f2bf(v[0]); o[1] = f2bf(v[1]); o[2] = f2bf(v[2]); o[3] = f2bf(v[3]);
  *(ushortx4*)(xb + i) = o;
}

// ---------------- transpose weights -> bf16 N x K ----------------
__global__ void transpose_w(const float* __restrict__ Wq, const float* __restrict__ Wk,
                            const float* __restrict__ Wv, const float* __restrict__ Wo,
                            unsigned short* __restrict__ Wqkvt, unsigned short* __restrict__ Wot) {
  __shared__ float tile[32][33];
  int z = blockIdx.z;
  const float* W = (z == 0) ? Wq : (z == 1) ? Wk : (z == 2) ? Wv : Wo;
  unsigned short* out = (z == 3) ? Wot : (Wqkvt + (size_t)z * 1024 * 1024);
  int n0 = blockIdx.x * 32, k0 = blockIdx.y * 32;
  int tx = threadIdx.x, ty = threadIdx.y;            // block (32,8)
#pragma unroll
  for (int j = 0; j < 4; ++j)
    tile[ty + j * 8][tx] = W[(size_t)(k0 + ty + j * 8) * 1024 + n0 + tx];
  __syncthreads();
#pragma unroll
  for (int j = 0; j < 4; ++j)
    out[(size_t)(n0 + ty + j * 8) * 1024 + k0 + tx] = f2bf(tile[tx][ty + j * 8]);
}

// ---------------- GEMM core v3: 64x128 tile, BK=64, XOR-swizzled LDS ----------------
#define GEMM_PROLOGUE()                                                        \
  __shared__ __align__(16) unsigned short As[64 * 64];                         \
  __shared__ __align__(16) unsigned short Bs[128 * 64];                        \
  const int tid = threadIdx.x;                                                 \
  const int lane = tid & 63;                                                   \
  const int wid = tid >> 6;                                                    \
  const int col = lane & 15;                                                   \
  const int quad = lane >> 4;                                                  \
  const int m0 = blockIdx.x * 64;                                              \
  const int n0 = blockIdx.y * 128;                                             \
  const int wm = wid >> 1;                                                     \
  const int wn = wid & 1;                                                      \
  floatx4 acc[2][4];                                                           \
  _Pragma("unroll") for (int i = 0; i < 2; ++i)                                \
      _Pragma("unroll") for (int j = 0; j < 4; ++j)                            \
          acc[i][j] = (floatx4)(0.f);                                          \
  _Pragma("unroll 1") for (int kt = 0; kt < 16; ++kt) {                        \
    __syncthreads();                                                           \
    _Pragma("unroll") for (int call = 0; call < 2; ++call) {                   \
      int c = call * 256 + tid;                                                \
      int r = c >> 3, ch = c & 7;                                              \
      gload_lds16(A + (size_t)(m0 + r) * 1024 + kt * 64 + ((ch ^ (r & 7)) * 8),\
                  As + (size_t)(call * 256 + wid * 64) * 8);                   \
    }                                                                          \
    _Pragma("unroll") for (int call = 0; call < 4; ++call) {                   \
      int c = call * 256 + tid;                                                \
      int r = c >> 3, ch = c & 7;                                              \
      gload_lds16(Bt + (size_t)(n0 + r) * 1024 + kt * 64 + ((ch ^ (r & 7)) * 8),\
                  Bs + (size_t)(call * 256 + wid * 64) * 8);                   \
    }                                                                          \
    __syncthreads();                                                           \
    _Pragma("unroll") for (int ks = 0; ks < 2; ++ks) {                         \
      short8 af[2], bf[4];                                                     \
      _Pragma("unroll") for (int rt = 0; rt < 2; ++rt) {                       \
        int row = wm * 32 + rt * 16 + col;                                     \
        af[rt] = *(const short8*)&As[row * 64 + (((ks * 4 + quad) ^ (row & 7)) * 8)]; \
      }                                                                        \
      _Pragma("unroll") for (int ct = 0; ct < 4; ++ct) {                       \
        int row = wn * 64 + ct * 16 + col;                                     \
        bf[ct] = *(const short8*)&Bs[row * 64 + (((ks * 4 + quad) ^ (row & 7)) * 8)]; \
      }                                                                        \
      _Pragma("unroll") for (int rt = 0; rt < 2; ++rt)                         \
          _Pragma("unroll") for (int ct = 0; ct < 4; ++ct)                     \
              acc[rt][ct] = MFMA16(af[rt], bf[ct], acc[rt][ct]);               \
    }                                                                          \
  }

__global__ __launch_bounds__(256, 5)
void gemm_qkv(const unsigned short* __restrict__ A, const unsigned short* __restrict__ Bt,
              const float* __restrict__ bq, const float* __restrict__ bk,
              const float* __restrict__ bv,
              unsigned short* __restrict__ Qo, unsigned short* __restrict__ Ko,
              unsigned short* __restrict__ Vo) {
  GEMM_PROLOGUE()
  const int nseg = n0 >> 10;
  const float* bias = (nseg == 0) ? bq : ((nseg == 1) ? bk : bv);
#pragma unroll
  for (int rt = 0; rt < 2; ++rt) {
#pragma unroll
    for (int ct = 0; ct < 4; ++ct) {
      int mg = m0 + wm * 32 + rt * 16 + quad * 4;
      int ng = n0 + wn * 64 + ct * 16 + col;
      int c = ng & 1023;
      int hh = c >> 6, hd = c & 63;
      int b_ = mg >> 11, s = mg & 2047;
      float bb = bias[c];
      if (nseg == 2) {
        ushortx4 pk;
#pragma unroll
        for (int i = 0; i < 4; ++i) pk[i] = f2bf(acc[rt][ct][i] + bb);
        *(ushortx4*)&Vo[(size_t)(b_ * 16 + hh) * 131072 + (size_t)hd * 2048 + s] = pk;
      } else {
        unsigned short* dst =
            ((nseg == 0) ? Qo : Ko) + ((size_t)(b_ * 16 + hh) * 2048 + s) * 64 + hd;
        float scl = (nseg == 0) ? 0.125f : 1.0f;    // fold 1/sqrt(64) into Q
#pragma unroll
        for (int i = 0; i < 4; ++i) dst[(size_t)i * 64] = f2bf((acc[rt][ct][i] + bb) * scl);
      }
    }
  }
}

__global__ __launch_bounds__(256, 5)
void gemm_out(const unsigned short* __restrict__ A, const unsigned short* __restrict__ Bt,
              const float* __restrict__ bo, float* __restrict__ Out) {
  GEMM_PROLOGUE()
#pragma unroll
  for (int rt = 0; rt < 2; ++rt) {
#pragma unroll
    for (int ct = 0; ct < 4; ++ct) {
      int mg = m0 + wm * 32 + rt * 16 + quad * 4;
      int ng = n0 + wn * 64 + ct * 16 + col;
      float bb = bo[ng];
#pragma unroll
      for (int i = 0; i < 4; ++i)
        Out[(size_t)(mg + i) * 1024 + ng] = acc[rt][ct][i] + bb;
    }
  }
}

// ---------------- flash attention v9: kv=128, K/Q direct-global, V staged ----------------
// Q-tile 64 (4 waves x 16 q rows), kv-tile 128. K frags and Q frags are contiguous
// b128 reads straight from global (no Ks LDS, no Q staging); only V^T is staged
// -> LDS 32 KiB (Vs+Ps), ONE barrier-pair per iter, 4+ blocks/CU resident.
// Grid 1024, longest tiles first.
__global__ __launch_bounds__(256, 4)
void flash_attn(const unsigned short* __restrict__ Q, const unsigned short* __restrict__ K,
                const unsigned short* __restrict__ Vt, const float* __restrict__ mask,
                unsigned short* __restrict__ O) {
  __shared__ __align__(16) unsigned short Vs[64 * 128];   // [hd][kv c16], chunk^(r&15)
  __shared__ __align__(16) unsigned short Ps[64 * 128];   // P [q][c16], chunk-swizzled

  const int tid = threadIdx.x;
  const int lane = tid & 63;
  const int wid = tid >> 6;
  const int col = lane & 15;
  const int quad = lane >> 4;
  const int j = 31 - (int)(blockIdx.x >> 5);  // q-tile (64 rows), longest first
  const int bh = blockIdx.x & 31;
  const int b = bh >> 4, h = bh & 15;
  const int q0 = j * 64;
  const int tdiag = j >> 1;                   // diagonal kv-tile (128 wide)

  const unsigned short* Qp = Q + (size_t)bh * 2048 * 64;
  const unsigned short* Kp = K + (size_t)bh * 2048 * 64;
  const unsigned short* Vp = Vt + (size_t)bh * 64 * 2048;
  const float* mp = mask + b * 2048;
  const int lr16 = lane >> 4, lc16 = lane & 15; // V staging lane coords
  const floatx4 fzero = (floatx4)(0.f);
  const floatx4 fone = (floatx4)(1.f);

  // Q fragments direct from global (B-op): q = q0 + wid*16 + col, k = ks*32+quad*8
  short8 qf[2];
#pragma unroll
  for (int ks = 0; ks < 2; ++ks)
    qf[ks] = *(const short8*)&Qp[(size_t)(q0 + wid * 16 + col) * 64 + ks * 32 + quad * 8];

  floatx4 o[4];
#pragma unroll
  for (int dt = 0; dt < 4; ++dt) o[dt] = fzero;
  float mrow = -1e30f;
  float lrow = 0.f;

#pragma unroll 1
  for (int t = 0; t <= tdiag; ++t) {
    if (t > 0) __syncthreads();  // prior iter's Vs/Ps reads done
    // stage V^T tile [64][128] (swizzled)
#pragma unroll
    for (int i = 0; i < 4; ++i) {
      int seg = wid * 4 + i;
      int r = seg * 4 + lr16;
      gload_lds16(Vp + (size_t)r * 2048 + t * 128 + ((lc16 ^ (r & 15)) * 8), Vs + seg * 512);
    }
    // K fragments direct from global (A-op): kv = t*128 + rt*16 + col, k = ks*32+quad*8
    short8 kf[8][2];
#pragma unroll
    for (int rt = 0; rt < 8; ++rt)
#pragma unroll
      for (int ks = 0; ks < 2; ++ks)
        kf[rt][ks] =
            *(const short8*)&Kp[(size_t)(t * 128 + rt * 16 + col) * 64 + ks * 32 + quad * 8];
    __syncthreads();  // Vs visible (barrier drains vmcnt -> kf also resident)

    // S^T: [kv=128][q=16 per wave] -- kf dies here, before mbias loads (reg pressure)
    floatx4 sc[8];
#pragma unroll
    for (int rt = 0; rt < 8; ++rt) {
      floatx4 s0 = MFMA16(kf[rt][0], qf[0], fzero);
      sc[rt] = MFMA16(kf[rt][1], qf[1], s0);
    }
    // padding-mask additive bias (kv = rt*16 + quad*4 + i), L1-resident
#pragma unroll
    for (int rt = 0; rt < 8; ++rt) {
      floatx4 mm = *(const floatx4*)&mp[t * 128 + rt * 16 + quad * 4];
      sc[rt] += (fone - mm) * -1.0e9f;
    }
    if (t == tdiag) {  // diagonal tile: causal mask, exactly -1e9 like the reference
      int qg = q0 + wid * 16 + col;
#pragma unroll
      for (int rt = 0; rt < 8; ++rt)
#pragma unroll
        for (int i = 0; i < 4; ++i)
          if (t * 128 + rt * 16 + quad * 4 + i > qg) sc[rt][i] = -1.0e9f;
    }

    // online softmax (per-lane q row stats; reduce over quad via 2 shuffles)
    float mt = -1e30f;
#pragma unroll
    for (int rt = 0; rt < 8; ++rt)
      mt = fmaxf(mt, fmaxf(fmaxf(sc[rt][0], sc[rt][1]), fmaxf(sc[rt][2], sc[rt][3])));
    mt = fmaxf(mt, __shfl_xor(mt, 16));
    mt = fmaxf(mt, __shfl_xor(mt, 32));
    float mn = fmaxf(mrow, mt);
    float alpha = __expf(mrow - mn);
    mrow = mn;
    float sum = 0.f;
#pragma unroll
    for (int rt = 0; rt < 8; ++rt)
#pragma unroll
      for (int i = 0; i < 4; ++i) {
        float p = __expf(sc[rt][i] - mn);
        sc[rt][i] = p;
        sum += p;
      }
    sum += __shfl_xor(sum, 16);
    sum += __shfl_xor(sum, 32);
    lrow = lrow * alpha + sum;
#pragma unroll
    for (int dt = 0; dt < 4; ++dt) o[dt] *= alpha;
    // write P rows (own wave) swizzled: 8B at chunk (rt*2 + quad>>1) ^ col, half quad&1
    {
      int qloc = wid * 16 + col;
#pragma unroll
      for (int rt = 0; rt < 8; ++rt) {
        ushortx4 pk;
#pragma unroll
        for (int i = 0; i < 4; ++i) pk[i] = f2bf(sc[rt][i]);
        int chunk = (rt * 2 + (quad >> 1)) ^ col;
        *(ushortx4*)&Ps[qloc * 128 + chunk * 8 + (quad & 1) * 4] = pk;
      }
    }
    // PV: O^T[d][q] += V^T * P^T (own-wave P rows; DS in-order per wave, no barrier)
#pragma unroll
    for (int ks = 0; ks < 4; ++ks) {
      int ch = ks * 4 + quad;
      short8 pf = *(const short8*)&Ps[(wid * 16 + col) * 128 + ((ch ^ col) * 8)];
#pragma unroll
      for (int dt = 0; dt < 4; ++dt) {
        short8 vf = *(const short8*)&Vs[(dt * 16 + col) * 128 + ((ch ^ col) * 8)];
        o[dt] = MFMA16(vf, pf, o[dt]);
      }
    }
  }

  // epilogue: O^T regs: d = dt*16 + quad*4 + i, q = wid*16 + col
  {
    float inv = 1.0f / lrow;
    int qg = q0 + wid * 16 + col;
    unsigned short* dst = O + ((size_t)(b * 2048 + qg)) * 1024 + h * 64;
#pragma unroll
    for (int dt = 0; dt < 4; ++dt) {
      ushortx4 pk;
#pragma unroll
      for (int i = 0; i < 4; ++i) pk[i] = f2bf(o[dt][i] * inv);
      *(ushortx4*)&dst[dt * 16 + quad * 4] = pk;
    }
  }
}

// ---------------- launch ----------------
extern "C" void kernel_launch(void* const* d_in, const int* in_sizes, int n_in,
                              void* d_out, int out_size, void* d_ws, size_t ws_size,
                              hipStream_t stream) {
  (void)in_sizes; (void)n_in; (void)out_size; (void)ws_size;
  const float* x  = (const float*)d_in[0];
  const float* mask = (const float*)d_in[1];
  const float* Wq = (const float*)d_in[2];
  const float* bq = (const float*)d_in[3];
  const float* Wk = (const float*)d_in[4];
  const float* bk = (const float*)d_in[5];
  const float* Wv = (const float*)d_in[6];
  const float* bv = (const float*)d_in[7];
  const float* Wo = (const float*)d_in[8];
  const float* bo = (const float*)d_in[9];
  float* out = (float*)d_out;

  char* ws = (char*)d_ws;
  unsigned short* xb    = (unsigned short*)(ws);                    // 8 MB
  unsigned short* Wqkvt = (unsigned short*)(ws + (8u << 20));       // 6 MB
  unsigned short* Wot   = (unsigned short*)(ws + (14u << 20));      // 2 MB
  unsigned short* Qb    = (unsigned short*)(ws + (16u << 20));      // 8 MB
  unsigned short* Kb    = (unsigned short*)(ws + (24u << 20));      // 8 MB
  unsigned short* Vtb   = (unsigned short*)(ws + (32u << 20));      // 8 MB
  unsigned short* Ao    = (unsigned short*)(ws + (40u << 20));      // 8 MB (48 MB total)

  convert_x<<<4096, 256, 0, stream>>>(x, xb);
  transpose_w<<<dim3(32, 32, 4), dim3(32, 8), 0, stream>>>(Wq, Wk, Wv, Wo, Wqkvt, Wot);
  gemm_qkv<<<dim3(64, 24), 256, 0, stream>>>(xb, Wqkvt, bq, bk, bv, Qb, Kb, Vtb);
  flash_attn<<<dim3(1024), 256, 0, stream>>>(Qb, Kb, Vtb, mask, Ao);
  gemm_out<<<dim3(64, 8), 256, 0, stream>>>(Ao, Wot, bo, out);
}

// Round 12
// 210.373 us; speedup vs baseline: 1.1991x; 1.1991x over previous
//
#include <hip/hip_runtime.h>
#include <hip/hip_bf16.h>
#include <cstdint>
#include <cstddef>

// ---- types ----
typedef __attribute__((ext_vector_type(8))) short short8;       // 8 bf16 (4 VGPR) MFMA frag
typedef __attribute__((ext_vector_type(4))) float floatx4;      // MFMA accumulator
typedef __attribute__((ext_vector_type(4))) unsigned short ushortx4; // 8B packed bf16 store
typedef __attribute__((ext_vector_type(2))) unsigned int uintx2;     // 8B vector st

#define MFMA16(a, b, c) __builtin_amdgcn_mfma_f32_16x16x32_bf16((a), (b), (c), 0, 0, 0)
#define LOG2E 1.44269504088896340736f
#define EXP2(x) __builtin_amdgcn_exp2f(x)

__device__ __forceinline__ unsigned short f2bf(float f) {
  unsigned int u = __builtin_bit_cast(unsigned int, f);
  u += 0x7fffu + ((u >> 16) & 1u);          // RNE
  return (unsigned short)(u >> 16);
}

// packed bf16 pair via v_cvt_pk_bf16_f32 (RNE); memcpy avoids bit_cast restriction
__device__ __forceinline__ unsigned int pk2(float a, float b) {
  float2 f; f.x = a; f.y = b;
  __hip_bfloat162 h = __float22bfloat162_rn(f);
  unsigned int u;
  __builtin_memcpy(&u, &h, 4);
  return u;
}

typedef __attribute__((address_space(1))) void gvoid_t;
typedef __attribute__((address_space(3))) void svoid_t;
__device__ __forceinline__ void gload_lds16(const void* g, void* l) {
  // LDS dest = wave-uniform base + lane*16; global side is per-lane addresses.
  __builtin_amdgcn_global_load_lds((gvoid_t*)(uintptr_t)g, (svoid_t*)(uintptr_t)l, 16, 0, 0);
}

// ---------------- convert x: fp32 -> bf16 ----------------
__global__ void convert_x(const float* __restrict__ x, unsigned short* __restrict__ xb) {
  int i = (blockIdx.x * 256 + threadIdx.x) * 4;
  floatx4 v = *(const floatx4*)(x + i);
  uintx2 o;
  o[0] = pk2(v[0], v[1]);
  o[1] = pk2(v[2], v[3]);
  *(uintx2*)(xb + i) = o;
}

// ---------------- transpose weights -> bf16 N x K ----------------
__global__ void transpose_w(const float* __restrict__ Wq, const float* __restrict__ Wk,
                            const float* __restrict__ Wv, const float* __restrict__ Wo,
                            unsigned short* __restrict__ Wqkvt, unsigned short* __restrict__ Wot) {
  __shared__ float tile[32][33];
  int z = blockIdx.z;
  const float* W = (z == 0) ? Wq : (z == 1) ? Wk : (z == 2) ? Wv : Wo;
  unsigned short* out = (z == 3) ? Wot : (Wqkvt + (size_t)z * 1024 * 1024);
  int n0 = blockIdx.x * 32, k0 = blockIdx.y * 32;
  int tx = threadIdx.x, ty = threadIdx.y;            // block (32,8)
#pragma unroll
  for (int j = 0; j < 4; ++j)
    tile[ty + j * 8][tx] = W[(size_t)(k0 + ty + j * 8) * 1024 + n0 + tx];
  __syncthreads();
#pragma unroll
  for (int j = 0; j < 4; ++j)
    out[(size_t)(n0 + ty + j * 8) * 1024 + k0 + tx] = f2bf(tile[tx][ty + j * 8]);
}

// ---------------- GEMM core v3: 64x128 tile, BK=64, XOR-swizzled LDS ----------------
#define GEMM_PROLOGUE()                                                        \
  __shared__ __align__(16) unsigned short As[64 * 64];                         \
  __shared__ __align__(16) unsigned short Bs[128 * 64];                        \
  const int tid = threadIdx.x;                                                 \
  const int lane = tid & 63;                                                   \
  const int wid = tid >> 6;                                                    \
  const int col = lane & 15;                                                   \
  const int quad = lane >> 4;                                                  \
  const int m0 = blockIdx.x * 64;                                              \
  const int n0 = blockIdx.y * 128;                                             \
  const int wm = wid >> 1;                                                     \
  const int wn = wid & 1;                                                      \
  floatx4 acc[2][4];                                                           \
  _Pragma("unroll") for (int i = 0; i < 2; ++i)                                \
      _Pragma("unroll") for (int j = 0; j < 4; ++j)                            \
          acc[i][j] = (floatx4)(0.f);                                          \
  _Pragma("unroll 1") for (int kt = 0; kt < 16; ++kt) {                        \
    __syncthreads();                                                           \
    _Pragma("unroll") for (int call = 0; call < 2; ++call) {                   \
      int c = call * 256 + tid;                                                \
      int r = c >> 3, ch = c & 7;                                              \
      gload_lds16(A + (size_t)(m0 + r) * 1024 + kt * 64 + ((ch ^ (r & 7)) * 8),\
                  As + (size_t)(call * 256 + wid * 64) * 8);                   \
    }                                                                          \
    _Pragma("unroll") for (int call = 0; call < 4; ++call) {                   \
      int c = call * 256 + tid;                                                \
      int r = c >> 3, ch = c & 7;                                              \
      gload_lds16(Bt + (size_t)(n0 + r) * 1024 + kt * 64 + ((ch ^ (r & 7)) * 8),\
                  Bs + (size_t)(call * 256 + wid * 64) * 8);                   \
    }                                                                          \
    __syncthreads();                                                           \
    _Pragma("unroll") for (int ks = 0; ks < 2; ++ks) {                         \
      short8 af[2], bf[4];                                                     \
      _Pragma("unroll") for (int rt = 0; rt < 2; ++rt) {                       \
        int row = wm * 32 + rt * 16 + col;                                     \
        af[rt] = *(const short8*)&As[row * 64 + (((ks * 4 + quad) ^ (row & 7)) * 8)]; \
      }                                                                        \
      _Pragma("unroll") for (int ct = 0; ct < 4; ++ct) {                       \
        int row = wn * 64 + ct * 16 + col;                                     \
        bf[ct] = *(const short8*)&Bs[row * 64 + (((ks * 4 + quad) ^ (row & 7)) * 8)]; \
      }                                                                        \
      _Pragma("unroll") for (int rt = 0; rt < 2; ++rt)                         \
          _Pragma("unroll") for (int ct = 0; ct < 4; ++ct)                     \
              acc[rt][ct] = MFMA16(af[rt], bf[ct], acc[rt][ct]);               \
    }                                                                          \
  }

__global__ __launch_bounds__(256, 5)
void gemm_qkv(const unsigned short* __restrict__ A, const unsigned short* __restrict__ Bt,
              const float* __restrict__ bq, const float* __restrict__ bk,
              const float* __restrict__ bv,
              unsigned short* __restrict__ Qo, unsigned short* __restrict__ Ko,
              unsigned short* __restrict__ Vo) {
  GEMM_PROLOGUE()
  const int nseg = n0 >> 10;
  const float* bias = (nseg == 0) ? bq : ((nseg == 1) ? bk : bv);
#pragma unroll
  for (int rt = 0; rt < 2; ++rt) {
#pragma unroll
    for (int ct = 0; ct < 4; ++ct) {
      int mg = m0 + wm * 32 + rt * 16 + quad * 4;
      int ng = n0 + wn * 64 + ct * 16 + col;
      int c = ng & 1023;
      int hh = c >> 6, hd = c & 63;
      int b_ = mg >> 11, s = mg & 2047;
      float bb = bias[c];
      if (nseg == 2) {
        uintx2 pk;
        pk[0] = pk2(acc[rt][ct][0] + bb, acc[rt][ct][1] + bb);
        pk[1] = pk2(acc[rt][ct][2] + bb, acc[rt][ct][3] + bb);
        *(uintx2*)&Vo[(size_t)(b_ * 16 + hh) * 131072 + (size_t)hd * 2048 + s] = pk;
      } else {
        unsigned short* dst =
            ((nseg == 0) ? Qo : Ko) + ((size_t)(b_ * 16 + hh) * 2048 + s) * 64 + hd;
        // Q scale folds 1/sqrt(64) AND log2(e) (exp2-domain softmax downstream)
        float scl = (nseg == 0) ? (0.125f * LOG2E) : 1.0f;
#pragma unroll
        for (int i = 0; i < 4; ++i) dst[(size_t)i * 64] = f2bf((acc[rt][ct][i] + bb) * scl);
      }
    }
  }
}

__global__ __launch_bounds__(256, 5)
void gemm_out(const unsigned short* __restrict__ A, const unsigned short* __restrict__ Bt,
              const float* __restrict__ bo, float* __restrict__ Out) {
  GEMM_PROLOGUE()
#pragma unroll
  for (int rt = 0; rt < 2; ++rt) {
#pragma unroll
    for (int ct = 0; ct < 4; ++ct) {
      int mg = m0 + wm * 32 + rt * 16 + quad * 4;
      int ng = n0 + wn * 64 + ct * 16 + col;
      float bb = bo[ng];
#pragma unroll
      for (int i = 0; i < 4; ++i)
        Out[(size_t)(mg + i) * 1024 + ng] = acc[rt][ct][i] + bb;
    }
  }
}

// ---------------- flash attention v10: v6 structure + 40K LDS + exp2 softmax ----------------
// Q-tile 64 (4 waves x 16 q rows), kv-tile 128, K/V staged via global_load_lds.
// Ps holds only ONE 64-kv half (8 KB, wave-private) -> LDS exactly 40 KiB ->
// 4 blocks/CU (16 waves/CU). Softmax in exp2 domain (log2e folded into Q scale).
// Grid 1024, longest tiles first.
__global__ __launch_bounds__(256, 4)
void flash_attn(const unsigned short* __restrict__ Q, const unsigned short* __restrict__ K,
                const unsigned short* __restrict__ Vt, const float* __restrict__ mask,
                unsigned short* __restrict__ O) {
  __shared__ __align__(16) unsigned short Ks[128 * 64];   // [kv][hd c8], chunk^(r&7)
  __shared__ __align__(16) unsigned short Vs[64 * 128];   // [hd][kv c16], chunk^(r&15)
  __shared__ __align__(16) unsigned short Ps[64 * 64];    // P half [q][64kv], chunk^(q&7); Q stage

  const int tid = threadIdx.x;
  const int lane = tid & 63;
  const int wid = tid >> 6;
  const int col = lane & 15;
  const int quad = lane >> 4;
  const int j = 31 - (int)(blockIdx.x >> 5);  // q-tile (64 rows), longest first
  const int bh = blockIdx.x & 31;
  const int b = bh >> 4, h = bh & 15;
  const int q0 = j * 64;
  const int tdiag = j >> 1;                   // diagonal kv-tile (128 wide)

  const unsigned short* Qp = Q + (size_t)bh * 2048 * 64;
  const unsigned short* Kp = K + (size_t)bh * 2048 * 64;
  const unsigned short* Vp = Vt + (size_t)bh * 64 * 2048;
  const float* mp = mask + b * 2048;

  const int lr8 = lane >> 3, lc8 = lane & 7;    // K/Q staging lane coords
  const int lr16 = lane >> 4, lc16 = lane & 15; // V staging lane coords
  const floatx4 fzero = (floatx4)(0.f);
  const floatx4 fone = (floatx4)(1.f);

  // stage Q rows [64][64] into Ps (swizzled): LDS[r][c] = Q[r][c ^ (r&7)]
#pragma unroll
  for (int i = 0; i < 2; ++i) {
    int seg = wid * 2 + i;
    int r = seg * 8 + lr8;
    gload_lds16(Qp + (size_t)(q0 + r) * 64 + ((lc8 ^ (r & 7)) * 8), Ps + seg * 512);
  }
  __syncthreads();  // staged Q visible
  short8 qf[2];
  {
    int q = wid * 16 + col;
#pragma unroll
    for (int ks = 0; ks < 2; ++ks)
      qf[ks] = *(const short8*)&Ps[q * 64 + (((ks * 4 + quad) ^ (q & 7)) * 8)];
  }
  // Waves only read their OWN 16 rows; P writes also own rows -> wave-private, no barrier.

  floatx4 o[4];
#pragma unroll
  for (int dt = 0; dt < 4; ++dt) o[dt] = fzero;
  float mrow = -1e30f;
  float lrow = 0.f;

#pragma unroll 1
  for (int t = 0; t <= tdiag; ++t) {
    if (t > 0) __syncthreads();  // prior iter's Ks/Vs frag reads done
#pragma unroll
    for (int i = 0; i < 4; ++i) {  // K tile [128][64]
      int seg = wid * 4 + i;
      int r = seg * 8 + lr8;
      gload_lds16(Kp + (size_t)(t * 128 + r) * 64 + ((lc8 ^ (r & 7)) * 8), Ks + seg * 512);
    }
#pragma unroll
    for (int i = 0; i < 4; ++i) {  // V^T tile [64][128]
      int seg = wid * 4 + i;
      int r = seg * 4 + lr16;
      gload_lds16(Vp + (size_t)r * 2048 + t * 128 + ((lc16 ^ (r & 15)) * 8), Vs + seg * 512);
    }
    __syncthreads();  // staging visible

    // padding-mask additive bias in exp2 domain (kv = rt*16 + quad*4 + i)
    floatx4 mbias[8];
#pragma unroll
    for (int rt = 0; rt < 8; ++rt) {
      floatx4 mm = *(const floatx4*)&mp[t * 128 + rt * 16 + quad * 4];
      mbias[rt] = (fone - mm) * (-1.0e9f * LOG2E);
    }

    // S^T: [kv=128][q=16 per wave]  (scores already x log2e via Q scale)
    floatx4 sc[8];
#pragma unroll
    for (int rt = 0; rt < 8; ++rt) {
      int kr = rt * 16 + col;
      short8 kf0 = *(const short8*)&Ks[kr * 64 + ((quad ^ (col & 7)) * 8)];
      short8 kf1 = *(const short8*)&Ks[kr * 64 + (((4 + quad) ^ (col & 7)) * 8)];
      floatx4 s0 = MFMA16(kf0, qf[0], fzero);
      s0 = MFMA16(kf1, qf[1], s0);
      sc[rt] = s0 + mbias[rt];
    }
    if (t == tdiag) {  // causal diagonal: -1e9 * log2e (exp2 domain)
      int qg = q0 + wid * 16 + col;
#pragma unroll
      for (int rt = 0; rt < 8; ++rt)
#pragma unroll
        for (int i = 0; i < 4; ++i)
          if (t * 128 + rt * 16 + quad * 4 + i > qg) sc[rt][i] = -1.0e9f * LOG2E;
    }

    // online softmax, exp2 domain (per-lane q row stats; 2 shuffles per reduce)
    float mt = -1e30f;
#pragma unroll
    for (int rt = 0; rt < 8; ++rt)
      mt = fmaxf(mt, fmaxf(fmaxf(sc[rt][0], sc[rt][1]), fmaxf(sc[rt][2], sc[rt][3])));
    mt = fmaxf(mt, __shfl_xor(mt, 16));
    mt = fmaxf(mt, __shfl_xor(mt, 32));
    float mn = fmaxf(mrow, mt);
    float alpha = EXP2(mrow - mn);
    mrow = mn;
    float sum = 0.f;
#pragma unroll
    for (int rt = 0; rt < 8; ++rt)
#pragma unroll
      for (int i = 0; i < 4; ++i) {
        float p = EXP2(sc[rt][i] - mn);
        sc[rt][i] = p;
        sum += p;
      }
    sum += __shfl_xor(sum, 16);
    sum += __shfl_xor(sum, 32);
    lrow = lrow * alpha + sum;
#pragma unroll
    for (int dt = 0; dt < 4; ++dt) o[dt] *= alpha;

    // PV in two kv-halves through the 8 KB wave-private Ps
    int qloc = wid * 16 + col;
#pragma unroll
    for (int half = 0; half < 2; ++half) {
      // write P half rows: kv granule (rt2*2 + quad>>1) ^ (q&7), sub (quad&1)*4
#pragma unroll
      for (int rt2 = 0; rt2 < 4; ++rt2) {
        int rt = half * 4 + rt2;
        uintx2 w;
        w[0] = pk2(sc[rt][0], sc[rt][1]);
        w[1] = pk2(sc[rt][2], sc[rt][3]);
        int chunk = (rt2 * 2 + (quad >> 1)) ^ (col & 7);
        *(uintx2*)&Ps[qloc * 64 + chunk * 8 + (quad & 1) * 4] = w;
      }
      // O^T[d][q] += V^T * P^T (own-wave P rows; DS in-order per wave)
#pragma unroll
      for (int ks2 = 0; ks2 < 2; ++ks2) {
        short8 pf = *(const short8*)&Ps[qloc * 64 + (((ks2 * 4 + quad) ^ (col & 7)) * 8)];
#pragma unroll
        for (int dt = 0; dt < 4; ++dt) {
          int vch = (half * 8 + ks2 * 4 + quad) ^ col;   // V row & 15 == col
          short8 vf = *(const short8*)&Vs[(dt * 16 + col) * 128 + vch * 8];
          o[dt] = MFMA16(vf, pf, o[dt]);
        }
      }
    }
  }

  // epilogue: O^T regs: d = dt*16 + quad*4 + i, q = wid*16 + col
  {
    float inv = 1.0f / lrow;
    int qg = q0 + wid * 16 + col;
    unsigned short* dst = O + ((size_t)(b * 2048 + qg)) * 1024 + h * 64;
#pragma unroll
    for (int dt = 0; dt < 4; ++dt) {
      uintx2 pk;
      pk[0] = pk2(o[dt][0] * inv, o[dt][1] * inv);
      pk[1] = pk2(o[dt][2] * inv, o[dt][3] * inv);
      *(uintx2*)&dst[dt * 16 + quad * 4] = pk;
    }
  }
}

// ---------------- launch ----------------
extern "C" void kernel_launch(void* const* d_in, const int* in_sizes, int n_in,
                              void* d_out, int out_size, void* d_ws, size_t ws_size,
                              hipStream_t stream) {
  (void)in_sizes; (void)n_in; (void)out_size; (void)ws_size;
  const float* x  = (const float*)d_in[0];
  const float* mask = (const float*)d_in[1];
  const float* Wq = (const float*)d_in[2];
  const float* bq = (const float*)d_in[3];
  const float* Wk = (const float*)d_in[4];
  const float* bk = (const float*)d_in[5];
  const float* Wv = (const float*)d_in[6];
  const float* bv = (const float*)d_in[7];
  const float* Wo = (const float*)d_in[8];
  const float* bo = (const float*)d_in[9];
  float* out = (float*)d_out;

  char* ws = (char*)d_ws;
  unsigned short* xb    = (unsigned short*)(ws);                    // 8 MB
  unsigned short* Wqkvt = (unsigned short*)(ws + (8u << 20));       // 6 MB
  unsigned short* Wot   = (unsigned short*)(ws + (14u << 20));      // 2 MB
  unsigned short* Qb    = (unsigned short*)(ws + (16u << 20));      // 8 MB
  unsigned short* Kb    = (unsigned short*)(ws + (24u << 20));      // 8 MB
  unsigned short* Vtb   = (unsigned short*)(ws + (32u << 20));      // 8 MB
  unsigned short* Ao    = (unsigned short*)(ws + (40u << 20));      // 8 MB (48 MB total)

  convert_x<<<4096, 256, 0, stream>>>(x, xb);
  transpose_w<<<dim3(32, 32, 4), dim3(32, 8), 0, stream>>>(Wq, Wk, Wv, Wo, Wqkvt, Wot);
  gemm_qkv<<<dim3(64, 24), 256, 0, stream>>>(xb, Wqkvt, bq, bk, bv, Qb, Kb, Vtb);
  flash_attn<<<dim3(1024), 256, 0, stream>>>(Qb, Kb, Vtb, mask, Ao);
  gemm_out<<<dim3(64, 8), 256, 0, stream>>>(Ao, Wot, bo, out);
}

// Round 13
// 183.165 us; speedup vs baseline: 1.3773x; 1.1485x over previous
//
#include <hip/hip_runtime.h>
#include <hip/hip_bf16.h>
#include <cstdint>
#include <cstddef>

// ---- types ----
typedef __attribute__((ext_vector_type(8))) short short8;       // 8 bf16 (4 VGPR) MFMA frag
typedef __attribute__((ext_vector_type(4))) float floatx4;      // MFMA accumulator
typedef __attribute__((ext_vector_type(4))) unsigned short ushortx4; // 8B packed bf16 store
typedef __attribute__((ext_vector_type(2))) unsigned int uintx2;     // 8B vector st

#define MFMA16(a, b, c) __builtin_amdgcn_mfma_f32_16x16x32_bf16((a), (b), (c), 0, 0, 0)
#define LOG2E 1.44269504088896340736f
#define EXP2(x) __builtin_amdgcn_exp2f(x)

__device__ __forceinline__ unsigned short f2bf(float f) {
  unsigned int u = __builtin_bit_cast(unsigned int, f);
  u += 0x7fffu + ((u >> 16) & 1u);          // RNE
  return (unsigned short)(u >> 16);
}

// packed bf16 pair via v_cvt_pk_bf16_f32 (RNE); memcpy avoids bit_cast restriction
__device__ __forceinline__ unsigned int pk2(float a, float b) {
  float2 f; f.x = a; f.y = b;
  __hip_bfloat162 h = __float22bfloat162_rn(f);
  unsigned int u;
  __builtin_memcpy(&u, &h, 4);
  return u;
}

typedef __attribute__((address_space(1))) void gvoid_t;
typedef __attribute__((address_space(3))) void svoid_t;
__device__ __forceinline__ void gload_lds16(const void* g, void* l) {
  // LDS dest = wave-uniform base + lane*16; global side is per-lane addresses.
  __builtin_amdgcn_global_load_lds((gvoid_t*)(uintptr_t)g, (svoid_t*)(uintptr_t)l, 16, 0, 0);
}

// ---------------- convert x: fp32 -> bf16 ----------------
__global__ void convert_x(const float* __restrict__ x, unsigned short* __restrict__ xb) {
  int i = (blockIdx.x * 256 + threadIdx.x) * 4;
  floatx4 v = *(const floatx4*)(x + i);
  uintx2 o;
  o[0] = pk2(v[0], v[1]);
  o[1] = pk2(v[2], v[3]);
  *(uintx2*)(xb + i) = o;
}

// ---------------- transpose weights -> bf16 N x K ----------------
__global__ void transpose_w(const float* __restrict__ Wq, const float* __restrict__ Wk,
                            const float* __restrict__ Wv, const float* __restrict__ Wo,
                            unsigned short* __restrict__ Wqkvt, unsigned short* __restrict__ Wot) {
  __shared__ float tile[32][33];
  int z = blockIdx.z;
  const float* W = (z == 0) ? Wq : (z == 1) ? Wk : (z == 2) ? Wv : Wo;
  unsigned short* out = (z == 3) ? Wot : (Wqkvt + (size_t)z * 1024 * 1024);
  int n0 = blockIdx.x * 32, k0 = blockIdx.y * 32;
  int tx = threadIdx.x, ty = threadIdx.y;            // block (32,8)
#pragma unroll
  for (int j = 0; j < 4; ++j)
    tile[ty + j * 8][tx] = W[(size_t)(k0 + ty + j * 8) * 1024 + n0 + tx];
  __syncthreads();
#pragma unroll
  for (int j = 0; j < 4; ++j)
    out[(size_t)(n0 + ty + j * 8) * 1024 + k0 + tx] = f2bf(tile[tx][ty + j * 8]);
}

// ---------------- GEMM core v3: 64x128 tile, BK=64, XOR-swizzled LDS ----------------
#define GEMM_PROLOGUE()                                                        \
  __shared__ __align__(16) unsigned short As[64 * 64];                         \
  __shared__ __align__(16) unsigned short Bs[128 * 64];                        \
  const int tid = threadIdx.x;                                                 \
  const int lane = tid & 63;                                                   \
  const int wid = tid >> 6;                                                    \
  const int col = lane & 15;                                                   \
  const int quad = lane >> 4;                                                  \
  const int m0 = blockIdx.x * 64;                                              \
  const int n0 = blockIdx.y * 128;                                             \
  const int wm = wid >> 1;                                                     \
  const int wn = wid & 1;                                                      \
  floatx4 acc[2][4];                                                           \
  _Pragma("unroll") for (int i = 0; i < 2; ++i)                                \
      _Pragma("unroll") for (int j = 0; j < 4; ++j)                            \
          acc[i][j] = (floatx4)(0.f);                                          \
  _Pragma("unroll 1") for (int kt = 0; kt < 16; ++kt) {                        \
    __syncthreads();                                                           \
    _Pragma("unroll") for (int call = 0; call < 2; ++call) {                   \
      int c = call * 256 + tid;                                                \
      int r = c >> 3, ch = c & 7;                                              \
      gload_lds16(A + (size_t)(m0 + r) * 1024 + kt * 64 + ((ch ^ (r & 7)) * 8),\
                  As + (size_t)(call * 256 + wid * 64) * 8);                   \
    }                                                                          \
    _Pragma("unroll") for (int call = 0; call < 4; ++call) {                   \
      int c = call * 256 + tid;                                                \
      int r = c >> 3, ch = c & 7;                                              \
      gload_lds16(Bt + (size_t)(n0 + r) * 1024 + kt * 64 + ((ch ^ (r & 7)) * 8),\
                  Bs + (size_t)(call * 256 + wid * 64) * 8);                   \
    }                                                                          \
    __syncthreads();                                                           \
    _Pragma("unroll") for (int ks = 0; ks < 2; ++ks) {                         \
      short8 af[2], bf[4];                                                     \
      _Pragma("unroll") for (int rt = 0; rt < 2; ++rt) {                       \
        int row = wm * 32 + rt * 16 + col;                                     \
        af[rt] = *(const short8*)&As[row * 64 + (((ks * 4 + quad) ^ (row & 7)) * 8)]; \
      }                                                                        \
      _Pragma("unroll") for (int ct = 0; ct < 4; ++ct) {                       \
        int row = wn * 64 + ct * 16 + col;                                     \
        bf[ct] = *(const short8*)&Bs[row * 64 + (((ks * 4 + quad) ^ (row & 7)) * 8)]; \
      }                                                                        \
      _Pragma("unroll") for (int rt = 0; rt < 2; ++rt)                         \
          _Pragma("unroll") for (int ct = 0; ct < 4; ++ct)                     \
              acc[rt][ct] = MFMA16(af[rt], bf[ct], acc[rt][ct]);               \
    }                                                                          \
  }

__global__ __launch_bounds__(256, 5)
void gemm_qkv(const unsigned short* __restrict__ A, const unsigned short* __restrict__ Bt,
              const float* __restrict__ bq, const float* __restrict__ bk,
              const float* __restrict__ bv,
              unsigned short* __restrict__ Qo, unsigned short* __restrict__ Ko,
              unsigned short* __restrict__ Vo) {
  GEMM_PROLOGUE()
  const int nseg = n0 >> 10;
  const float* bias = (nseg == 0) ? bq : ((nseg == 1) ? bk : bv);
#pragma unroll
  for (int rt = 0; rt < 2; ++rt) {
#pragma unroll
    for (int ct = 0; ct < 4; ++ct) {
      int mg = m0 + wm * 32 + rt * 16 + quad * 4;
      int ng = n0 + wn * 64 + ct * 16 + col;
      int c = ng & 1023;
      int hh = c >> 6, hd = c & 63;
      int b_ = mg >> 11, s = mg & 2047;
      float bb = bias[c];
      if (nseg == 2) {
        uintx2 pk;
        pk[0] = pk2(acc[rt][ct][0] + bb, acc[rt][ct][1] + bb);
        pk[1] = pk2(acc[rt][ct][2] + bb, acc[rt][ct][3] + bb);
        *(uintx2*)&Vo[(size_t)(b_ * 16 + hh) * 131072 + (size_t)hd * 2048 + s] = pk;
      } else {
        unsigned short* dst =
            ((nseg == 0) ? Qo : Ko) + ((size_t)(b_ * 16 + hh) * 2048 + s) * 64 + hd;
        // Q scale folds 1/sqrt(64) AND log2(e) (exp2-domain softmax downstream)
        float scl = (nseg == 0) ? (0.125f * LOG2E) : 1.0f;
#pragma unroll
        for (int i = 0; i < 4; ++i) dst[(size_t)i * 64] = f2bf((acc[rt][ct][i] + bb) * scl);
      }
    }
  }
}

__global__ __launch_bounds__(256, 5)
void gemm_out(const unsigned short* __restrict__ A, const unsigned short* __restrict__ Bt,
              const float* __restrict__ bo, float* __restrict__ Out) {
  GEMM_PROLOGUE()
#pragma unroll
  for (int rt = 0; rt < 2; ++rt) {
#pragma unroll
    for (int ct = 0; ct < 4; ++ct) {
      int mg = m0 + wm * 32 + rt * 16 + quad * 4;
      int ng = n0 + wn * 64 + ct * 16 + col;
      float bb = bo[ng];
#pragma unroll
      for (int i = 0; i < 4; ++i)
        Out[(size_t)(mg + i) * 1024 + ng] = acc[rt][ct][i] + bb;
    }
  }
}

// ---------------- flash attention v11 = R8's v6 structure + exp2 + packed cvt ----------------
// Q-tile 64 (4 waves x 16 q rows), kv-tile 128, K/V staged via global_load_lds,
// full 16 KB Ps (one write->read round trip per iter). LDS 48 KiB, lb(256,3),
// grid 1024 (one tile/block), longest tiles first.
__global__ __launch_bounds__(256, 3)
void flash_attn(const unsigned short* __restrict__ Q, const unsigned short* __restrict__ K,
                const unsigned short* __restrict__ Vt, const float* __restrict__ mask,
                unsigned short* __restrict__ O) {
  __shared__ __align__(16) unsigned short Ks[128 * 64];   // [kv][hd c8], chunk^(r&7)
  __shared__ __align__(16) unsigned short Vs[64 * 128];   // [hd][kv c16], chunk^(r&15)
  __shared__ __align__(16) unsigned short Ps[64 * 128];   // P [q][c16] swizzled; Q stage [64][64]

  const int tid = threadIdx.x;
  const int lane = tid & 63;
  const int wid = tid >> 6;
  const int col = lane & 15;
  const int quad = lane >> 4;
  const int j = 31 - (int)(blockIdx.x >> 5);  // q-tile (64 rows), longest first
  const int bh = blockIdx.x & 31;
  const int b = bh >> 4, h = bh & 15;
  const int q0 = j * 64;
  const int tdiag = j >> 1;                   // diagonal kv-tile (128 wide)

  const unsigned short* Qp = Q + (size_t)bh * 2048 * 64;
  const unsigned short* Kp = K + (size_t)bh * 2048 * 64;
  const unsigned short* Vp = Vt + (size_t)bh * 64 * 2048;
  const float* mp = mask + b * 2048;

  const int lr8 = lane >> 3, lc8 = lane & 7;    // K/Q staging lane coords
  const int lr16 = lane >> 4, lc16 = lane & 15; // V staging lane coords
  const floatx4 fzero = (floatx4)(0.f);
  const floatx4 fone = (floatx4)(1.f);

  // stage Q rows [64][64] into Ps (swizzled): LDS[r][c] = Q[r][c ^ (r&7)]
#pragma unroll
  for (int i = 0; i < 2; ++i) {
    int seg = wid * 2 + i;
    int r = seg * 8 + lr8;
    gload_lds16(Qp + (size_t)(q0 + r) * 64 + ((lc8 ^ (r & 7)) * 8), Ps + seg * 512);
  }
  __syncthreads();  // staged Q visible
  short8 qf[2];
  {
    int q = wid * 16 + col;
#pragma unroll
    for (int ks = 0; ks < 2; ++ks)
      qf[ks] = *(const short8*)&Ps[q * 64 + (((ks * 4 + quad) ^ (q & 7)) * 8)];
  }
  // First P write is ordered after all waves' qf reads by the t=0 post-staging barrier.

  floatx4 o[4];
#pragma unroll
  for (int dt = 0; dt < 4; ++dt) o[dt] = fzero;
  float mrow = -1e30f;
  float lrow = 0.f;

#pragma unroll 1
  for (int t = 0; t <= tdiag; ++t) {
    if (t > 0) __syncthreads();  // prior iter's Ks/Vs frag reads done
#pragma unroll
    for (int i = 0; i < 4; ++i) {  // K tile [128][64]
      int seg = wid * 4 + i;
      int r = seg * 8 + lr8;
      gload_lds16(Kp + (size_t)(t * 128 + r) * 64 + ((lc8 ^ (r & 7)) * 8), Ks + seg * 512);
    }
#pragma unroll
    for (int i = 0; i < 4; ++i) {  // V^T tile [64][128]
      int seg = wid * 4 + i;
      int r = seg * 4 + lr16;
      gload_lds16(Vp + (size_t)r * 2048 + t * 128 + ((lc16 ^ (r & 15)) * 8), Vs + seg * 512);
    }
    __syncthreads();  // staging visible

    // padding-mask additive bias, exp2 domain (kv = rt*16 + quad*4 + i)
    floatx4 mbias[8];
#pragma unroll
    for (int rt = 0; rt < 8; ++rt) {
      floatx4 mm = *(const floatx4*)&mp[t * 128 + rt * 16 + quad * 4];
      mbias[rt] = (fone - mm) * (-1.0e9f * LOG2E);
    }

    // S^T: [kv=128][q=16 per wave]  (scores already x log2e via Q scale)
    floatx4 sc[8];
#pragma unroll
    for (int rt = 0; rt < 8; ++rt) {
      int kr = rt * 16 + col;
      short8 kf0 = *(const short8*)&Ks[kr * 64 + ((quad ^ (col & 7)) * 8)];
      short8 kf1 = *(const short8*)&Ks[kr * 64 + (((4 + quad) ^ (col & 7)) * 8)];
      floatx4 s0 = MFMA16(kf0, qf[0], fzero);
      s0 = MFMA16(kf1, qf[1], s0);
      sc[rt] = s0 + mbias[rt];
    }
    if (t == tdiag) {  // causal diagonal: -1e9 * log2e (exp2 domain)
      int qg = q0 + wid * 16 + col;
#pragma unroll
      for (int rt = 0; rt < 8; ++rt)
#pragma unroll
        for (int i = 0; i < 4; ++i)
          if (t * 128 + rt * 16 + quad * 4 + i > qg) sc[rt][i] = -1.0e9f * LOG2E;
    }

    // online softmax, exp2 domain (per-lane q row stats; 2 shuffles per reduce)
    float mt = -1e30f;
#pragma unroll
    for (int rt = 0; rt < 8; ++rt)
      mt = fmaxf(mt, fmaxf(fmaxf(sc[rt][0], sc[rt][1]), fmaxf(sc[rt][2], sc[rt][3])));
    mt = fmaxf(mt, __shfl_xor(mt, 16));
    mt = fmaxf(mt, __shfl_xor(mt, 32));
    float mn = fmaxf(mrow, mt);
    float alpha = EXP2(mrow - mn);
    mrow = mn;
    float sum = 0.f;
#pragma unroll
    for (int rt = 0; rt < 8; ++rt)
#pragma unroll
      for (int i = 0; i < 4; ++i) {
        float p = EXP2(sc[rt][i] - mn);
        sc[rt][i] = p;
        sum += p;
      }
    sum += __shfl_xor(sum, 16);
    sum += __shfl_xor(sum, 32);
    lrow = lrow * alpha + sum;
#pragma unroll
    for (int dt = 0; dt < 4; ++dt) o[dt] *= alpha;
    // write P rows (own wave) swizzled: 8B at chunk (rt*2 + quad>>1) ^ col, half quad&1
    {
      int qloc = wid * 16 + col;
#pragma unroll
      for (int rt = 0; rt < 8; ++rt) {
        uintx2 w;
        w[0] = pk2(sc[rt][0], sc[rt][1]);
        w[1] = pk2(sc[rt][2], sc[rt][3]);
        int chunk = (rt * 2 + (quad >> 1)) ^ col;
        *(uintx2*)&Ps[qloc * 128 + chunk * 8 + (quad & 1) * 4] = w;
      }
    }
    // PV: O^T[d][q] += V^T * P^T (own-wave P rows; DS in-order per wave, no barrier)
#pragma unroll
    for (int ks = 0; ks < 4; ++ks) {
      int ch = ks * 4 + quad;
      short8 pf = *(const short8*)&Ps[(wid * 16 + col) * 128 + ((ch ^ col) * 8)];
#pragma unroll
      for (int dt = 0; dt < 4; ++dt) {
        short8 vf = *(const short8*)&Vs[(dt * 16 + col) * 128 + ((ch ^ col) * 8)];
        o[dt] = MFMA16(vf, pf, o[dt]);
      }
    }
  }

  // epilogue: O^T regs: d = dt*16 + quad*4 + i, q = wid*16 + col
  {
    float inv = 1.0f / lrow;
    int qg = q0 + wid * 16 + col;
    unsigned short* dst = O + ((size_t)(b * 2048 + qg)) * 1024 + h * 64;
#pragma unroll
    for (int dt = 0; dt < 4; ++dt) {
      uintx2 pk;
      pk[0] = pk2(o[dt][0] * inv, o[dt][1] * inv);
      pk[1] = pk2(o[dt][2] * inv, o[dt][3] * inv);
      *(uintx2*)&dst[dt * 16 + quad * 4] = pk;
    }
  }
}

// ---------------- launch ----------------
extern "C" void kernel_launch(void* const* d_in, const int* in_sizes, int n_in,
                              void* d_out, int out_size, void* d_ws, size_t ws_size,
                              hipStream_t stream) {
  (void)in_sizes; (void)n_in; (void)out_size; (void)ws_size;
  const float* x  = (const float*)d_in[0];
  const float* mask = (const float*)d_in[1];
  const float* Wq = (const float*)d_in[2];
  const float* bq = (const float*)d_in[3];
  const float* Wk = (const float*)d_in[4];
  const float* bk = (const float*)d_in[5];
  const float* Wv = (const float*)d_in[6];
  const float* bv = (const float*)d_in[7];
  const float* Wo = (const float*)d_in[8];
  const float* bo = (const float*)d_in[9];
  float* out = (float*)d_out;

  char* ws = (char*)d_ws;
  unsigned short* xb    = (unsigned short*)(ws);                    // 8 MB
  unsigned short* Wqkvt = (unsigned short*)(ws + (8u << 20));       // 6 MB
  unsigned short* Wot   = (unsigned short*)(ws + (14u << 20));      // 2 MB
  unsigned short* Qb    = (unsigned short*)(ws + (16u << 20));      // 8 MB
  unsigned short* Kb    = (unsigned short*)(ws + (24u << 20));      // 8 MB
  unsigned short* Vtb   = (unsigned short*)(ws + (32u << 20));      // 8 MB
  unsigned short* Ao    = (unsigned short*)(ws + (40u << 20));      // 8 MB (48 MB total)

  convert_x<<<4096, 256, 0, stream>>>(x, xb);
  transpose_w<<<dim3(32, 32, 4), dim3(32, 8), 0, stream>>>(Wq, Wk, Wv, Wo, Wqkvt, Wot);
  gemm_qkv<<<dim3(64, 24), 256, 0, stream>>>(xb, Wqkvt, bq, bk, bv, Qb, Kb, Vtb);
  flash_attn<<<dim3(1024), 256, 0, stream>>>(Qb, Kb, Vtb, mask, Ao);
  gemm_out<<<dim3(64, 8), 256, 0, stream>>>(Ao, Wot, bo, out);
}